// Round 1
// baseline (2110.511 us; speedup 1.0000x reference)
//
#include <hip/hip_runtime.h>
#include <math.h>

#define NRTOK 16384   // Nr
#define MMAX 64       // M
#define AD 128        // ADIM
#define HD 512        // HID

__device__ __forceinline__ void fma4(float4& a, float s, const float4& w) {
    a.x = fmaf(s, w.x, a.x); a.y = fmaf(s, w.y, a.y);
    a.z = fmaf(s, w.z, a.z); a.w = fmaf(s, w.w, a.w);
}

__device__ __forceinline__ float gelu_exact(float x) {
    return 0.5f * x * (1.f + erff(x * 0.70710678118654752440f));
}

// ---------------- Kernel 1: per-token masked attention + residual + LN1 ----------------
// grid = B*Nr blocks, 256 threads. Writes x (post-LN1) to xout.
__global__ __launch_bounds__(256) void attn_ln1(
    const float* __restrict__ Q, const float* __restrict__ K,
    const float* __restrict__ V, const int* __restrict__ mask,
    const float* __restrict__ g1, const float* __restrict__ b1,
    float* __restrict__ xout)
{
    __shared__ float sKV[MMAX * AD];   // 32 KB: K tile, then reused for V tile
    __shared__ float sQ[AD];
    __shared__ float sP[4 * MMAX];     // logits -> probs, [h][m]
    __shared__ int   sMask[MMAX];
    __shared__ float sAcc[2 * AD];     // PV partials (two m-halves)
    __shared__ float sRed[2];          // mu, rstd

    const int t = threadIdx.x;
    const long tok = blockIdx.x;                // 0..32767
    const int n = (int)(tok & (NRTOK - 1));

    const float4* K4 = (const float4*)(K + tok * (long)(MMAX * AD));
    const float4* V4 = (const float4*)(V + tok * (long)(MMAX * AD));
    float4* sKV4 = (float4*)sKV;

    if (t < AD) sQ[t] = Q[tok * AD + t];
    else if (t < AD + MMAX) sMask[t - AD] = mask[n * MMAX + (t - AD)];

    // stage K tile coalesced: 2048 float4
    #pragma unroll
    for (int i = 0; i < 8; ++i) sKV4[t + 256 * i] = K4[t + 256 * i];
    __syncthreads();

    // logits: thread -> (m = t>>2, h = t&3); bank-swizzled d walk (2-way, free)
    {
        const int m = t >> 2, h = t & 3;
        const float* krow = sKV + m * AD + h * 32;
        const float* qrow = sQ + h * 32;
        float acc = 0.f;
        #pragma unroll
        for (int i = 0; i < 32; ++i) {
            const int d = (i + 8 * h + m) & 31;
            acc = fmaf(qrow[d], krow[d], acc);
        }
        float logit = acc * 0.17677669529663687f;  // 1/sqrt(32)
        if (sMask[m] != 0) logit = -__builtin_inff();
        sP[h * MMAX + m] = logit;
    }
    __syncthreads();

    // prefetch V into registers while softmax executes
    float4 vreg[8];
    #pragma unroll
    for (int i = 0; i < 8; ++i) vreg[i] = V4[t + 256 * i];

    // softmax: wave w owns head w (64 m values over 64 lanes)
    {
        const int w = t >> 6, l = t & 63;
        float v = sP[w * MMAX + l];
        float mx = v;
        #pragma unroll
        for (int off = 32; off >= 1; off >>= 1)
            mx = fmaxf(mx, __shfl_xor(mx, off, 64));
        float e = (mx > -__builtin_inff()) ? __expf(v - mx) : 0.f;
        float s = e;
        #pragma unroll
        for (int off = 32; off >= 1; off >>= 1)
            s += __shfl_xor(s, off, 64);
        sP[w * MMAX + l] = (s > 0.f) ? e / s : 0.f;
    }

    // stage V tile (overwrites K tile; logits reads completed before prior barrier)
    #pragma unroll
    for (int i = 0; i < 8; ++i) sKV4[t + 256 * i] = vreg[i];
    __syncthreads();

    // PV: o = (h,d), split m range in half across the two thread-halves
    {
        const int o = t & 127, half = t >> 7;
        const int h = o >> 5, d = o & 31;
        const float* vcol = sKV + h * 32 + d;
        const float* pr = sP + h * MMAX + half * 32;
        float acc = 0.f;
        #pragma unroll
        for (int m2 = 0; m2 < 32; ++m2)
            acc = fmaf(pr[m2], vcol[(half * 32 + m2) * AD], acc);
        sAcc[half * AD + o] = acc;
    }
    __syncthreads();

    // residual + LN1 stats (wave 0)
    if (t < 64) {
        float v0 = sQ[t]      + sAcc[t]       + sAcc[AD + t];
        float v1 = sQ[t + 64] + sAcc[t + 64]  + sAcc[AD + t + 64];
        float s = v0 + v1;
        float sq = fmaf(v0, v0, v1 * v1);
        #pragma unroll
        for (int off = 32; off >= 1; off >>= 1) {
            s  += __shfl_xor(s, off, 64);
            sq += __shfl_xor(sq, off, 64);
        }
        if (t == 0) {
            float mu = s * (1.f / 128.f);
            float var = sq * (1.f / 128.f) - mu * mu;
            sRed[0] = mu;
            sRed[1] = rsqrtf(var + 1e-5f);
        }
    }
    __syncthreads();

    if (t < AD) {
        float val = sQ[t] + sAcc[t] + sAcc[AD + t];
        float x = (val - sRed[0]) * sRed[1] * g1[t] + b1[t];
        xout[tok * AD + t] = x;
    }
}

// ---------------- Kernel 2: LN2 + MLP (128->512 gelu ->128) + residual ----------------
// grid = (B*Nr)/16 blocks, 256 threads, 16 tokens per block. In-place on xio.
__global__ __launch_bounds__(256) void mlp_k(
    float* __restrict__ xio,
    const float* __restrict__ g2, const float* __restrict__ b2g,
    const float* __restrict__ W1, const float* __restrict__ b1h,
    const float* __restrict__ W2, const float* __restrict__ b2o)
{
    __shared__ float sX[16 * AD];   // 8 KB  (kept for residual)
    __shared__ float sY[16 * AD];   // 8 KB  (LN2 output)
    __shared__ float sW[8 * HD];    // 16 KB (W1 8-k chunk / W2 32-j chunk)
    __shared__ float sH[16 * HD];   // 32 KB (hidden, post-gelu)
    // total exactly 64 KB

    const int t = threadIdx.x;
    const long base = (long)blockIdx.x * (16 * AD);

    // ---- load X (coalesced), LN2 in registers ----
    {
        const int token = t >> 4, j16 = t & 15;
        const float* xp = xio + base + token * AD + j16 * 8;
        float4 a = ((const float4*)xp)[0];
        float4 b = ((const float4*)xp)[1];
        ((float4*)(sX + token * AD + j16 * 8))[0] = a;
        ((float4*)(sX + token * AD + j16 * 8))[1] = b;
        float s  = a.x + a.y + a.z + a.w + b.x + b.y + b.z + b.w;
        float sq = a.x*a.x + a.y*a.y + a.z*a.z + a.w*a.w
                 + b.x*b.x + b.y*b.y + b.z*b.z + b.w*b.w;
        #pragma unroll
        for (int off = 8; off >= 1; off >>= 1) {   // reduce within 16-lane group
            s  += __shfl_xor(s, off, 64);
            sq += __shfl_xor(sq, off, 64);
        }
        float mu = s * (1.f / 128.f);
        float rstd = rsqrtf(sq * (1.f / 128.f) - mu * mu + 1e-5f);
        float4 ga  = ((const float4*)(g2  + j16 * 8))[0];
        float4 gb  = ((const float4*)(g2  + j16 * 8))[1];
        float4 bba = ((const float4*)(b2g + j16 * 8))[0];
        float4 bbb = ((const float4*)(b2g + j16 * 8))[1];
        float4 ya, yb;
        ya.x = (a.x - mu) * rstd * ga.x + bba.x;
        ya.y = (a.y - mu) * rstd * ga.y + bba.y;
        ya.z = (a.z - mu) * rstd * ga.z + bba.z;
        ya.w = (a.w - mu) * rstd * ga.w + bba.w;
        yb.x = (b.x - mu) * rstd * gb.x + bbb.x;
        yb.y = (b.y - mu) * rstd * gb.y + bbb.y;
        yb.z = (b.z - mu) * rstd * gb.z + bbb.z;
        yb.w = (b.w - mu) * rstd * gb.w + bbb.w;
        ((float4*)(sY + token * AD + j16 * 8))[0] = ya;
        ((float4*)(sY + token * AD + j16 * 8))[1] = yb;
    }
    __syncthreads();

    const int jt = t & 31;        // hid/out quad index
    const int tg = t >> 5;        // 0..7 -> tokens 2tg, 2tg+1
    const int tok0 = 2 * tg, tok1 = 2 * tg + 1;

    // ---- GEMM1: H[16][512] = Y @ W1, thread tile 2 tok x 16 hid ----
    float4 acc[2][4];
    #pragma unroll
    for (int a_ = 0; a_ < 2; ++a_)
        #pragma unroll
        for (int s_ = 0; s_ < 4; ++s_) acc[a_][s_] = make_float4(0.f, 0.f, 0.f, 0.f);

    for (int kc = 0; kc < 16; ++kc) {           // 8 k-rows per chunk
        const float4* wg = (const float4*)(W1 + (long)kc * 8 * HD);
        float4* sw4 = (float4*)sW;
        #pragma unroll
        for (int i = 0; i < 4; ++i) sw4[t + 256 * i] = wg[t + 256 * i];
        __syncthreads();
        #pragma unroll
        for (int k = 0; k < 8; ++k) {
            const float y0 = sY[tok0 * AD + kc * 8 + k];
            const float y1 = sY[tok1 * AD + kc * 8 + k];
            #pragma unroll
            for (int seg = 0; seg < 4; ++seg) {
                const float4 w = ((const float4*)(sW + k * HD + seg * 128))[jt];
                fma4(acc[0][seg], y0, w);
                fma4(acc[1][seg], y1, w);
            }
        }
        __syncthreads();
    }

    // ---- bias + exact gelu -> sH ----
    #pragma unroll
    for (int seg = 0; seg < 4; ++seg) {
        const float4 bb = ((const float4*)(b1h + seg * 128))[jt];
        #pragma unroll
        for (int a_ = 0; a_ < 2; ++a_) {
            float4 h = acc[a_][seg];
            h.x = gelu_exact(h.x + bb.x);
            h.y = gelu_exact(h.y + bb.y);
            h.z = gelu_exact(h.z + bb.z);
            h.w = gelu_exact(h.w + bb.w);
            const int token = (a_ == 0) ? tok0 : tok1;
            ((float4*)(sH + token * HD + seg * 128))[jt] = h;
        }
    }

    // ---- GEMM2: O[16][128] = gelu(H) @ W2, thread tile 2 tok x 4 out ----
    float4 acc2[2];
    acc2[0] = make_float4(0.f, 0.f, 0.f, 0.f);
    acc2[1] = make_float4(0.f, 0.f, 0.f, 0.f);

    for (int jc = 0; jc < 16; ++jc) {           // 32 j-rows per chunk
        const float4* wg = (const float4*)(W2 + (long)jc * 32 * AD);
        float4* sw4 = (float4*)sW;
        #pragma unroll
        for (int i = 0; i < 4; ++i) sw4[t + 256 * i] = wg[t + 256 * i];
        __syncthreads();
        #pragma unroll
        for (int jj = 0; jj < 32; ++jj) {
            const float h0 = sH[tok0 * HD + jc * 32 + jj];
            const float h1 = sH[tok1 * HD + jc * 32 + jj];
            const float4 w = ((const float4*)(sW + jj * AD))[jt];
            fma4(acc2[0], h0, w);
            fma4(acc2[1], h1, w);
        }
        __syncthreads();
    }

    // ---- epilogue: out = x + (H@W2 + b2) ----
    {
        const float4 bo = ((const float4*)b2o)[jt];
        #pragma unroll
        for (int a_ = 0; a_ < 2; ++a_) {
            const int token = (a_ == 0) ? tok0 : tok1;
            const float4 xr = ((const float4*)(sX + token * AD))[jt];
            float4 o;
            o.x = xr.x + acc2[a_].x + bo.x;
            o.y = xr.y + acc2[a_].y + bo.y;
            o.z = xr.z + acc2[a_].z + bo.z;
            o.w = xr.w + acc2[a_].w + bo.w;
            ((float4*)(xio + base + token * AD))[jt] = o;
        }
    }
}

extern "C" void kernel_launch(void* const* d_in, const int* in_sizes, int n_in,
                              void* d_out, int out_size, void* d_ws, size_t ws_size,
                              hipStream_t stream) {
    const float* Q    = (const float*)d_in[0];
    const float* K    = (const float*)d_in[1];
    const float* V    = (const float*)d_in[2];
    const int*   mask = (const int*)  d_in[3];
    const float* g1   = (const float*)d_in[4];
    const float* b1   = (const float*)d_in[5];
    const float* g2   = (const float*)d_in[6];
    const float* b2g  = (const float*)d_in[7];
    const float* W1   = (const float*)d_in[8];
    const float* b1h  = (const float*)d_in[9];
    const float* W2   = (const float*)d_in[10];
    const float* b2o  = (const float*)d_in[11];
    float* out = (float*)d_out;

    const int ntok = 2 * NRTOK;   // B * Nr = 32768
    attn_ln1<<<ntok, 256, 0, stream>>>(Q, K, V, mask, g1, b1, out);
    mlp_k<<<ntok / 16, 256, 0, stream>>>(out, g2, b2g, W1, b1h, W2, b2o);
}